// Round 8
// baseline (176.233 us; speedup 1.0000x reference)
//
#include <hip/hip_runtime.h>
#include <hip/hip_bf16.h>
#include <stdint.h>

typedef unsigned short u16;
typedef __attribute__((ext_vector_type(8))) short bf16x8;
typedef __attribute__((ext_vector_type(4))) float f32x4;

#define AS1 __attribute__((address_space(1)))
#define AS3 __attribute__((address_space(3)))

__device__ __forceinline__ void gload_lds16(const void* g, void* l) {
  __builtin_amdgcn_global_load_lds((const AS1 void*)g, (AS3 void*)l, 16, 0, 0);
}

__device__ __forceinline__ u16 f2bf(float f) {
  union { float f; uint32_t u; } v; v.f = f;
  uint32_t r = v.u + 0x7FFFu + ((v.u >> 16) & 1u);
  return (u16)(r >> 16);
}

// ---------------- fp32 -> bf16 ----------------
__global__ void cvt_bf16(const float* __restrict__ in, u16* __restrict__ out, int n4) {
  int i = blockIdx.x * blockDim.x + threadIdx.x;
  if (i >= n4) return;
  float4 v = ((const float4*)in)[i];
  uint64_t pk = (uint64_t)f2bf(v.x) | ((uint64_t)f2bf(v.y) << 16) |
                ((uint64_t)f2bf(v.z) << 32) | ((uint64_t)f2bf(v.w) << 48);
  ((uint64_t*)out)[i] = pk;
}

// ---------------- B^T GEMM: C[m][n] = sum_k A[m][k]*Bw[n][k] + bias[n] ----------------
#define BM 128
#define BN 128
#define BK 32

template<int MODE>
__global__ __launch_bounds__(256, 2)
void gemm_bt(const u16* __restrict__ A, const u16* __restrict__ Bw,
             const float* __restrict__ bias0, const float* __restrict__ bias1,
             const float* __restrict__ bias2, void* __restrict__ Out,
             int M, int N, int K)
{
  __shared__ __align__(16) u16 As[BM * BK];
  __shared__ __align__(16) u16 Bs[BN * BK];
  const int tid = threadIdx.x;
  const int lane = tid & 63, wid = tid >> 6;
  const int lr = lane & 15, lg = lane >> 4;
  const int m0 = blockIdx.y * BM, n0 = blockIdx.x * BN;
  const int z = blockIdx.z;
  const u16* Bz = Bw + (size_t)z * N * K;
  const float* bias = (MODE == 0) ? (z == 0 ? bias0 : (z == 1 ? bias1 : bias2)) : bias0;
  const int wm = (wid >> 1) * 64, wn = (wid & 1) * 64;

  f32x4 acc[4][4] = {};

  for (int kt = 0; kt < K; kt += BK) {
    __syncthreads();
#pragma unroll
    for (int i = 0; i < 2; ++i) {
      int cb = (i * 4 + wid) * 64;          // wave-uniform chunk base
      int c = cb + lane;
      int row = c >> 2, kc = (c & 3) * 8;   // 4 x 16B chunks per 32-elem row
      gload_lds16(A  + (size_t)(m0 + row) * K + kt + kc, (void*)&As[(size_t)cb * 8]);
      gload_lds16(Bz + (size_t)(n0 + row) * K + kt + kc, (void*)&Bs[(size_t)cb * 8]);
    }
    __syncthreads();

    bf16x8 af[4], bfr[4];
#pragma unroll
    for (int mf = 0; mf < 4; ++mf) af[mf]  = *(const bf16x8*)&As[(wm + mf * 16 + lr) * BK + lg * 8];
#pragma unroll
    for (int nf = 0; nf < 4; ++nf) bfr[nf] = *(const bf16x8*)&Bs[(wn + nf * 16 + lr) * BK + lg * 8];
#pragma unroll
    for (int mf = 0; mf < 4; ++mf)
#pragma unroll
      for (int nf = 0; nf < 4; ++nf)
        acc[mf][nf] = __builtin_amdgcn_mfma_f32_16x16x32_bf16(af[mf], bfr[nf], acc[mf][nf], 0, 0, 0);
  }

#pragma unroll
  for (int nf = 0; nf < 4; ++nf) {
    float bv = bias[n0 + wn + nf * 16 + lr];
#pragma unroll
    for (int mf = 0; mf < 4; ++mf)
#pragma unroll
      for (int r = 0; r < 4; ++r) {
        int m = m0 + wm + mf * 16 + lg * 4 + r;
        int n = n0 + wn + nf * 16 + lr;
        float v = acc[mf][nf][r] + bv;
        if (MODE == 0) {
          size_t addr = ((size_t)(m >> 11) * 16 + (n >> 6)) * (size_t)(2048 * 64)
                      + (size_t)(m & 2047) * 64 + (n & 63);
          ((u16*)Out)[(size_t)z * 4194304 + addr] = f2bf(v);
        } else {
          ((float*)Out)[(size_t)m * N + n] = v;
        }
      }
  }
}

// ---------------- V (B,H,T,d) -> Vt (B,H,d,T) ----------------
__global__ void transpose_v(const u16* __restrict__ v, u16* __restrict__ vt) {
  __shared__ __align__(16) u16 t[64][72];
  const int tid = threadIdx.x;
  const int s0 = blockIdx.x * 64;
  const int bh = blockIdx.y;
  const u16* src = v + (size_t)bh * 2048 * 64;
  u16* dst = vt + (size_t)bh * 64 * 2048;
#pragma unroll
  for (int i = 0; i < 2; ++i) {
    int c = tid + i * 256;
    int r = c >> 3, col = (c & 7) * 8;
    *(bf16x8*)&t[r][col] = *(const bf16x8*)&src[(size_t)(s0 + r) * 64 + col];
  }
  __syncthreads();
#pragma unroll
  for (int i = 0; i < 2; ++i) {
    int c = tid + i * 256;
    int d = c >> 3, sc = (c & 7) * 8;
    bf16x8 o;
#pragma unroll
    for (int j = 0; j < 8; ++j) o[j] = (short)t[sc + j][d];
    *(bf16x8*)&dst[(size_t)d * 2048 + s0 + sc] = o;
  }
}

// ---------------- causal flash attention ----------------
// grid (32, B*H), 256 thr = 4 waves; block owns 64 q-rows (wave: 16); 64-key tiles.
// K/V staged via global_load_lds into double-buffered, XOR-swizzled LDS:
//   LDS[row][slot] holds global chunk (slot ^ (row&7)); reads apply the same XOR.
// Counted vmcnt(4) keeps next tile's 4 loads in flight across barriers.
__global__ __launch_bounds__(256, 3)
void attn_fwd(const u16* __restrict__ q, const u16* __restrict__ k,
              const u16* __restrict__ vt, u16* __restrict__ y)
{
  __shared__ __align__(16) u16 Ks[2][64 * 64];
  __shared__ __align__(16) u16 Vs[2][64 * 64];
  __shared__ __align__(16) u16 Ps[4][16 * 72];   // per-wave P tile (pad 8)
  const int tid = threadIdx.x, lane = tid & 63, wid = tid >> 6;
  const int lr = lane & 15, lg = lane >> 4;
  const int qt = 31 - ((blockIdx.x + blockIdx.y) & 31);
  const int q0 = qt * 64;
  const int bh = blockIdx.y;
  const u16* qg = q + (size_t)bh * 2048 * 64;
  const u16* kg = k + (size_t)bh * 2048 * 64;
  const u16* vg = vt + (size_t)bh * 64 * 2048;
  const int trow0 = q0 + wid * 16;

  bf16x8 qa[2];
#pragma unroll
  for (int kk = 0; kk < 2; ++kk)
    qa[kk] = *(const bf16x8*)&qg[(size_t)(trow0 + lr) * 64 + kk * 32 + lg * 8];

  // staging source addresses (pre-swizzled): lane covers row l8 (+0/+8), slot s8;
  // stored content at slot s8 is global chunk (s8 ^ (row&7)) = (s8 ^ l8).
  const int l8 = lane >> 3, s8 = lane & 7;
  const int xs = s8 ^ l8;
  const u16* ksrc0 = kg + (size_t)(wid * 16 + l8) * 64 + xs * 8;
  const u16* vsrc0 = vg + (size_t)(wid * 16 + l8) * 2048 + xs * 8;

#define STAGE(t, buf) do {                                                    \
    const u16* ks_ = ksrc0 + (size_t)(t) * 4096;                              \
    const u16* vs_ = vsrc0 + (size_t)(t) * 64;                                \
    gload_lds16(ks_,            (void*)&Ks[buf][(wid * 16) * 64]);            \
    gload_lds16(ks_ + 512,      (void*)&Ks[buf][(wid * 16 + 8) * 64]);        \
    gload_lds16(vs_,            (void*)&Vs[buf][(wid * 16) * 64]);            \
    gload_lds16(vs_ + 8 * 2048, (void*)&Vs[buf][(wid * 16 + 8) * 64]);        \
  } while (0)

  f32x4 oacc[4] = {};
  float mrun[4], lrun[4];
#pragma unroll
  for (int r = 0; r < 4; ++r) { mrun[r] = -1e30f; lrun[r] = 0.f; }

  const int nkt = qt + 1;
  STAGE(0, 0);
  if (nkt > 1) STAGE(1, 1);

  const int xsl = lr & 7;                      // (row&7) for rows sf*16+lr

  for (int kt = 0; kt < nkt; ++kt) {
    if (kt + 1 < nkt) asm volatile("s_waitcnt vmcnt(4)" ::: "memory");
    else              asm volatile("s_waitcnt vmcnt(0)" ::: "memory");
    __builtin_amdgcn_s_barrier();

    const u16* Kb = &Ks[kt & 1][0];
    const u16* Vb = &Vs[kt & 1][0];

    f32x4 sacc[4] = {};
#pragma unroll
    for (int kk = 0; kk < 2; ++kk) {
      bf16x8 kb[4];
#pragma unroll
      for (int sf = 0; sf < 4; ++sf)
        kb[sf] = *(const bf16x8*)&Kb[(sf * 16 + lr) * 64 + (((kk * 4 + lg) ^ xsl) * 8)];
#pragma unroll
      for (int sf = 0; sf < 4; ++sf)
        sacc[sf] = __builtin_amdgcn_mfma_f32_16x16x32_bf16(qa[kk], kb[sf], sacc[sf], 0, 0, 0);
    }

    if (kt == qt) {                     // only the diagonal tile needs masking
#pragma unroll
      for (int sf = 0; sf < 4; ++sf)
#pragma unroll
        for (int r = 0; r < 4; ++r) {
          int t = trow0 + lg * 4 + r;
          int s = kt * 64 + sf * 16 + lr;
          float v = sacc[sf][r] * 0.125f;
          sacc[sf][r] = (s > t) ? -1e30f : v;
        }
    } else {
#pragma unroll
      for (int sf = 0; sf < 4; ++sf)
#pragma unroll
        for (int r = 0; r < 4; ++r) sacc[sf][r] *= 0.125f;
    }

    // online softmax: row (lg*4+r); reduce across the 16 lr lanes
    float sc[4];
#pragma unroll
    for (int r = 0; r < 4; ++r) {
      float mx = fmaxf(fmaxf(sacc[0][r], sacc[1][r]), fmaxf(sacc[2][r], sacc[3][r]));
#pragma unroll
      for (int off = 1; off < 16; off <<= 1) mx = fmaxf(mx, __shfl_xor(mx, off));
      float mn = fmaxf(mrun[r], mx);
      sc[r] = __expf(mrun[r] - mn);
      mrun[r] = mn;
      float rs = 0.f;
#pragma unroll
      for (int sf = 0; sf < 4; ++sf) {
        float p = __expf(sacc[sf][r] - mn);
        sacc[sf][r] = p;
        rs += p;
      }
#pragma unroll
      for (int off = 1; off < 16; off <<= 1) rs += __shfl_xor(rs, off);
      lrun[r] = lrun[r] * sc[r] + rs;
    }
#pragma unroll
    for (int nf = 0; nf < 4; ++nf)
#pragma unroll
      for (int r = 0; r < 4; ++r) oacc[nf][r] *= sc[r];
#pragma unroll
    for (int sf = 0; sf < 4; ++sf)
#pragma unroll
      for (int r = 0; r < 4; ++r)
        Ps[wid][(lg * 4 + r) * 72 + sf * 16 + lr] = f2bf(sacc[sf][r]);

    // PV: O[t][n] += P[t][s] * Vt[n][s]
#pragma unroll
    for (int kk = 0; kk < 2; ++kk) {
      bf16x8 pa, vb[4];
      pa = *(const bf16x8*)&Ps[wid][lr * 72 + kk * 32 + lg * 8];
#pragma unroll
      for (int nf = 0; nf < 4; ++nf)
        vb[nf] = *(const bf16x8*)&Vb[(nf * 16 + lr) * 64 + (((kk * 4 + lg) ^ xsl) * 8)];
#pragma unroll
      for (int nf = 0; nf < 4; ++nf)
        oacc[nf] = __builtin_amdgcn_mfma_f32_16x16x32_bf16(pa, vb[nf], oacc[nf], 0, 0, 0);
    }

    // all my LDS reads retired before anyone overwrites this buffer
    asm volatile("s_waitcnt lgkmcnt(0)" ::: "memory");
    __builtin_amdgcn_s_barrier();
    if (kt + 2 < nkt) STAGE(kt + 2, kt & 1);
  }
#undef STAGE

  const int b = bh >> 4, h = bh & 15;
#pragma unroll
  for (int r = 0; r < 4; ++r) {
    float inv = 1.f / lrun[r];
    int t = trow0 + lg * 4 + r;
#pragma unroll
    for (int nf = 0; nf < 4; ++nf) {
      int n = nf * 16 + lr;
      y[((size_t)b * 2048 + t) * 1024 + h * 64 + n] = f2bf(oacc[nf][r] * inv);
    }
  }
}

extern "C" void kernel_launch(void* const* d_in, const int* in_sizes, int n_in,
                              void* d_out, int out_size, void* d_ws, size_t ws_size,
                              hipStream_t stream) {
  const float* x  = (const float*)d_in[0];
  const float* Wq = (const float*)d_in[1];
  const float* bq = (const float*)d_in[2];
  const float* Wk = (const float*)d_in[3];
  const float* bk = (const float*)d_in[4];
  const float* Wv = (const float*)d_in[5];
  const float* bv = (const float*)d_in[6];
  const float* Wp = (const float*)d_in[7];
  const float* bp = (const float*)d_in[8];

  char* ws = (char*)d_ws;
  u16* x16  = (u16*)(ws + (size_t)0);          // 4096x1024 bf16 (reused as y16 later)
  u16* w16  = (u16*)(ws + ((size_t)8  << 20)); // Wq,Wk,Wv,Wp bf16, 1M elems each
  u16* q16  = (u16*)(ws + ((size_t)16 << 20)); // (B,H,T,d)
  u16* k16  = (u16*)(ws + ((size_t)24 << 20)); // (B,H,T,d)
  u16* v16  = (u16*)(ws + ((size_t)32 << 20)); // (B,H,T,d)
  u16* vt16 = (u16*)(ws + ((size_t)40 << 20)); // (B,H,d,T)
  u16* y16  = x16;

  cvt_bf16<<<4096, 256, 0, stream>>>(x,  x16, 1048576);
  cvt_bf16<<<1024, 256, 0, stream>>>(Wq, w16 + 0 * 1048576, 262144);
  cvt_bf16<<<1024, 256, 0, stream>>>(Wk, w16 + 1 * 1048576, 262144);
  cvt_bf16<<<1024, 256, 0, stream>>>(Wv, w16 + 2 * 1048576, 262144);
  cvt_bf16<<<1024, 256, 0, stream>>>(Wp, w16 + 3 * 1048576, 262144);

  gemm_bt<0><<<dim3(8, 32, 3), 256, 0, stream>>>(x16, w16, bq, bk, bv, (void*)q16, 4096, 1024, 1024);
  transpose_v<<<dim3(32, 32), 256, 0, stream>>>(v16, vt16);
  attn_fwd<<<dim3(32, 32), 256, 0, stream>>>(q16, k16, vt16, y16);
  gemm_bt<1><<<dim3(8, 32, 1), 256, 0, stream>>>(y16, w16 + 3 * 1048576, bp, bp, bp, d_out, 4096, 1024, 1024);
}

// Round 9
// 137.796 us; speedup vs baseline: 1.2789x; 1.2789x over previous
//
#include <hip/hip_runtime.h>
#include <hip/hip_bf16.h>
#include <stdint.h>

typedef unsigned short u16;
typedef __attribute__((ext_vector_type(8))) short bf16x8;
typedef __attribute__((ext_vector_type(4))) float f32x4;

#define AS1 __attribute__((address_space(1)))
#define AS3 __attribute__((address_space(3)))

__device__ __forceinline__ void gload_lds16(const void* g, void* l) {
  __builtin_amdgcn_global_load_lds((const AS1 void*)g, (AS3 void*)l, 16, 0, 0);
}

__device__ __forceinline__ u16 f2bf(float f) {
  union { float f; uint32_t u; } v; v.f = f;
  uint32_t r = v.u + 0x7FFFu + ((v.u >> 16) & 1u);
  return (u16)(r >> 16);
}

// ---------------- fp32 -> bf16 ----------------
__global__ void cvt_bf16(const float* __restrict__ in, u16* __restrict__ out, int n4) {
  int i = blockIdx.x * blockDim.x + threadIdx.x;
  if (i >= n4) return;
  float4 v = ((const float4*)in)[i];
  uint64_t pk = (uint64_t)f2bf(v.x) | ((uint64_t)f2bf(v.y) << 16) |
                ((uint64_t)f2bf(v.z) << 32) | ((uint64_t)f2bf(v.w) << 48);
  ((uint64_t*)out)[i] = pk;
}

// ---------------- B^T GEMM: C[m][n] = sum_k A[m][k]*Bw[n][k] + bias[n] ----------------
// MODE 0: bf16 out, scatter to (B,H,T,d); z selects {q,k,v}; Q scaled by 0.125.
// MODE 1: fp32 out, linear [m][n].
#define BM 128
#define BN 128
#define BK 32

template<int MODE>
__global__ __launch_bounds__(256, 2)
void gemm_bt(const u16* __restrict__ A, const u16* __restrict__ Bw,
             const float* __restrict__ bias0, const float* __restrict__ bias1,
             const float* __restrict__ bias2, void* __restrict__ Out,
             int M, int N, int K)
{
  __shared__ __align__(16) u16 As[BM * BK];
  __shared__ __align__(16) u16 Bs[BN * BK];
  const int tid = threadIdx.x;
  const int lane = tid & 63, wid = tid >> 6;
  const int lr = lane & 15, lg = lane >> 4;
  const int m0 = blockIdx.y * BM, n0 = blockIdx.x * BN;
  const int z = blockIdx.z;
  const u16* Bz = Bw + (size_t)z * N * K;
  const float* bias = (MODE == 0) ? (z == 0 ? bias0 : (z == 1 ? bias1 : bias2)) : bias0;
  const int wm = (wid >> 1) * 64, wn = (wid & 1) * 64;

  f32x4 acc[4][4] = {};

  for (int kt = 0; kt < K; kt += BK) {
    __syncthreads();
#pragma unroll
    for (int i = 0; i < 2; ++i) {
      int cb = (i * 4 + wid) * 64;          // wave-uniform chunk base
      int c = cb + lane;
      int row = c >> 2, kc = (c & 3) * 8;   // 4 x 16B chunks per 32-elem row
      gload_lds16(A  + (size_t)(m0 + row) * K + kt + kc, (void*)&As[(size_t)cb * 8]);
      gload_lds16(Bz + (size_t)(n0 + row) * K + kt + kc, (void*)&Bs[(size_t)cb * 8]);
    }
    __syncthreads();

    bf16x8 af[4], bfr[4];
#pragma unroll
    for (int mf = 0; mf < 4; ++mf) af[mf]  = *(const bf16x8*)&As[(wm + mf * 16 + lr) * BK + lg * 8];
#pragma unroll
    for (int nf = 0; nf < 4; ++nf) bfr[nf] = *(const bf16x8*)&Bs[(wn + nf * 16 + lr) * BK + lg * 8];
#pragma unroll
    for (int mf = 0; mf < 4; ++mf)
#pragma unroll
      for (int nf = 0; nf < 4; ++nf)
        acc[mf][nf] = __builtin_amdgcn_mfma_f32_16x16x32_bf16(af[mf], bfr[nf], acc[mf][nf], 0, 0, 0);
  }

#pragma unroll
  for (int nf = 0; nf < 4; ++nf) {
    float bv = bias[n0 + wn + nf * 16 + lr];
#pragma unroll
    for (int mf = 0; mf < 4; ++mf)
#pragma unroll
      for (int r = 0; r < 4; ++r) {
        int m = m0 + wm + mf * 16 + lg * 4 + r;
        int n = n0 + wn + nf * 16 + lr;
        float v = acc[mf][nf][r] + bv;
        if (MODE == 0) {
          if (z == 0) v *= 0.125f;     // fold 1/sqrt(d) into Q
          size_t addr = ((size_t)(m >> 11) * 16 + (n >> 6)) * (size_t)(2048 * 64)
                      + (size_t)(m & 2047) * 64 + (n & 63);
          ((u16*)Out)[(size_t)z * 4194304 + addr] = f2bf(v);
        } else {
          ((float*)Out)[(size_t)m * N + n] = v;
        }
      }
  }
}

// ---------------- V (B,H,T,d) -> Vt (B,H,d,T) ----------------
__global__ void transpose_v(const u16* __restrict__ v, u16* __restrict__ vt) {
  __shared__ __align__(16) u16 t[64][72];
  const int tid = threadIdx.x;
  const int s0 = blockIdx.x * 64;
  const int bh = blockIdx.y;
  const u16* src = v + (size_t)bh * 2048 * 64;
  u16* dst = vt + (size_t)bh * 64 * 2048;
#pragma unroll
  for (int i = 0; i < 2; ++i) {
    int c = tid + i * 256;
    int r = c >> 3, col = (c & 7) * 8;
    *(bf16x8*)&t[r][col] = *(const bf16x8*)&src[(size_t)(s0 + r) * 64 + col];
  }
  __syncthreads();
#pragma unroll
  for (int i = 0; i < 2; ++i) {
    int c = tid + i * 256;
    int d = c >> 3, sc = (c & 7) * 8;
    bf16x8 o;
#pragma unroll
    for (int j = 0; j < 8; ++j) o[j] = (short)t[sc + j][d];
    *(bf16x8*)&dst[(size_t)d * 2048 + s0 + sc] = o;
  }
}

// ---------------- causal flash attention ----------------
// grid (32, B*H), 256 thr = 4 waves; block owns 64 q-rows (wave: 16); 64-key tiles.
// Single-buffer LDS + T14 async staging: global->reg loads for kt+1 issued
// before compute of kt; ds_write at top. Raw barriers + manual lgkmcnt keep
// the prefetch vmcnt alive across barriers.
// Swapped QK^T: mfma(K,Q) -> each lane owns one q-row t=trow0+(lane&15);
// softmax reduce = in-register + 2 shfl_xor over the lg axis.
__global__ __launch_bounds__(256, 4)
void attn_fwd(const u16* __restrict__ q, const u16* __restrict__ k,
              const u16* __restrict__ vt, u16* __restrict__ y)
{
  __shared__ __align__(16) u16 Ks[64 * 64];     // XOR-swizzled: slot = chunk ^ (row&7)
  __shared__ __align__(16) u16 Vs[64 * 64];
  __shared__ __align__(16) u16 Ps[4][16 * 72];  // per-wave P tile (pad 8)
  const int tid = threadIdx.x, lane = tid & 63, wid = tid >> 6;
  const int lr = lane & 15, lg = lane >> 4;
  const int qt = 31 - ((blockIdx.x + blockIdx.y) & 31);
  const int q0 = qt * 64;
  const int bh = blockIdx.y;
  const u16* qg = q + (size_t)bh * 2048 * 64;
  const u16* kg = k + (size_t)bh * 2048 * 64;
  const u16* vg = vt + (size_t)bh * 64 * 2048;
  const int trow0 = q0 + wid * 16;

  bf16x8 qa[2];                                  // Q pre-scaled by 0.125 in GEMM
#pragma unroll
  for (int kk = 0; kk < 2; ++kk)
    qa[kk] = *(const bf16x8*)&qg[(size_t)(trow0 + lr) * 64 + kk * 32 + lg * 8];

  // staging: thread covers rows wid*16+l8 and +8, 16B chunk s8 (linear global).
  const int l8 = lane >> 3, s8 = lane & 7;
  const int r0 = wid * 16 + l8;
  const u16* kld = kg + (size_t)r0 * 64 + s8 * 8;
  const u16* vld = vg + (size_t)r0 * 2048 + s8 * 8;
  u16* kst0 = &Ks[r0 * 64 + (s8 ^ l8) * 8];      // (r0+8)&7 == l8 too
  u16* kst1 = &Ks[(r0 + 8) * 64 + (s8 ^ l8) * 8];
  u16* vst0 = &Vs[r0 * 64 + (s8 ^ l8) * 8];
  u16* vst1 = &Vs[(r0 + 8) * 64 + (s8 ^ l8) * 8];

  bf16x8 ldK0, ldK1, ldV0, ldV1;
  ldK0 = *(const bf16x8*)(kld);
  ldK1 = *(const bf16x8*)(kld + 8 * 64);
  ldV0 = *(const bf16x8*)(vld);
  ldV1 = *(const bf16x8*)(vld + 8 * 2048);

  f32x4 oacc[4] = {};
  float mrun = -1e30f, lrun = 0.f;               // state for q-row t = trow0+lr
  const int nkt = qt + 1;
  const int xsl = lr & 7;
  const int tq = trow0 + lr;

  for (int kt = 0; kt < nkt; ++kt) {
    // write staged regs -> LDS (swizzled)
    *(bf16x8*)kst0 = ldK0;  *(bf16x8*)kst1 = ldK1;
    *(bf16x8*)vst0 = ldV0;  *(bf16x8*)vst1 = ldV1;
    // issue next tile's loads; latency hides under this tile's compute
    if (kt + 1 < nkt) {
      const u16* kn = kld + (size_t)(kt + 1) * 4096;
      const u16* vn = vld + (size_t)(kt + 1) * 64;
      ldK0 = *(const bf16x8*)(kn);
      ldK1 = *(const bf16x8*)(kn + 8 * 64);
      ldV0 = *(const bf16x8*)(vn);
      ldV1 = *(const bf16x8*)(vn + 8 * 2048);
    }
    asm volatile("s_waitcnt lgkmcnt(0)" ::: "memory");   // my ds_writes done
    __builtin_amdgcn_s_barrier();                        // tile visible to all

    // QK^T swapped: sacc[sf][r] = S[s=kt*64+sf*16+lg*4+r][t=tq]
    f32x4 sacc[4] = {};
#pragma unroll
    for (int kk = 0; kk < 2; ++kk) {
      bf16x8 kb[4];
#pragma unroll
      for (int sf = 0; sf < 4; ++sf)
        kb[sf] = *(const bf16x8*)&Ks[(sf * 16 + lr) * 64 + (((kk * 4 + lg) ^ xsl) * 8)];
#pragma unroll
      for (int sf = 0; sf < 4; ++sf)
        sacc[sf] = __builtin_amdgcn_mfma_f32_16x16x32_bf16(kb[sf], qa[kk], sacc[sf], 0, 0, 0);
    }

    if (kt == qt) {                     // diagonal tile: mask s > t
#pragma unroll
      for (int sf = 0; sf < 4; ++sf)
#pragma unroll
        for (int r = 0; r < 4; ++r) {
          int s = kt * 64 + sf * 16 + lg * 4 + r;
          if (s > tq) sacc[sf][r] = -1e30f;
        }
    }

    // online softmax for row tq: in-register max/sum + 2-step lg reduce
    float mx = -1e30f;
#pragma unroll
    for (int sf = 0; sf < 4; ++sf)
#pragma unroll
      for (int r = 0; r < 4; ++r) mx = fmaxf(mx, sacc[sf][r]);
    mx = fmaxf(mx, __shfl_xor(mx, 16));
    mx = fmaxf(mx, __shfl_xor(mx, 32));
    float mn = fmaxf(mrun, mx);
    float scn = __expf(mrun - mn);
    mrun = mn;
    float rs = 0.f;
#pragma unroll
    for (int sf = 0; sf < 4; ++sf)
#pragma unroll
      for (int r = 0; r < 4; ++r) {
        float p = __expf(sacc[sf][r] - mn);
        sacc[sf][r] = p;
        rs += p;
      }
    rs += __shfl_xor(rs, 16);
    rs += __shfl_xor(rs, 32);
    lrun = lrun * scn + rs;

    // rescale O: oacc rows are t = trow0 + lg*4 + r -> fetch scn from lane lg*4+r
    float scr[4];
#pragma unroll
    for (int r = 0; r < 4; ++r) scr[r] = __shfl(scn, lg * 4 + r);
#pragma unroll
    for (int nf = 0; nf < 4; ++nf)
#pragma unroll
      for (int r = 0; r < 4; ++r) oacc[nf][r] *= scr[r];

    // P -> LDS: row t=lr, cols sf*16+lg*4+{0..3} as one 8B store each
#pragma unroll
    for (int sf = 0; sf < 4; ++sf) {
      union { ushort4 u; uint2 d; } pk_;
      pk_.u.x = f2bf(sacc[sf][0]); pk_.u.y = f2bf(sacc[sf][1]);
      pk_.u.z = f2bf(sacc[sf][2]); pk_.u.w = f2bf(sacc[sf][3]);
      *(uint2*)&Ps[wid][lr * 72 + sf * 16 + lg * 4] = pk_.d;
    }

    // PV: O[t][n] += P[t][s] * Vt[n][s]
#pragma unroll
    for (int kk = 0; kk < 2; ++kk) {
      bf16x8 pa, vb[4];
      pa = *(const bf16x8*)&Ps[wid][lr * 72 + kk * 32 + lg * 8];
#pragma unroll
      for (int nf = 0; nf < 4; ++nf)
        vb[nf] = *(const bf16x8*)&Vs[(nf * 16 + lr) * 64 + (((kk * 4 + lg) ^ xsl) * 8)];
#pragma unroll
      for (int nf = 0; nf < 4; ++nf)
        oacc[nf] = __builtin_amdgcn_mfma_f32_16x16x32_bf16(pa, vb[nf], oacc[nf], 0, 0, 0);
    }

    asm volatile("s_waitcnt lgkmcnt(0)" ::: "memory");   // my K/V reads retired
    __builtin_amdgcn_s_barrier();                        // safe to overwrite
  }

  const int b = bh >> 4, h = bh & 15;
#pragma unroll
  for (int r = 0; r < 4; ++r) {
    float lshf = __shfl(lrun, lg * 4 + r);
    float inv = 1.f / lshf;
    int t = trow0 + lg * 4 + r;
#pragma unroll
    for (int nf = 0; nf < 4; ++nf) {
      int n = nf * 16 + lr;
      y[((size_t)b * 2048 + t) * 1024 + h * 64 + n] = f2bf(oacc[nf][r] * inv);
    }
  }
}

extern "C" void kernel_launch(void* const* d_in, const int* in_sizes, int n_in,
                              void* d_out, int out_size, void* d_ws, size_t ws_size,
                              hipStream_t stream) {
  const float* x  = (const float*)d_in[0];
  const float* Wq = (const float*)d_in[1];
  const float* bq = (const float*)d_in[2];
  const float* Wk = (const float*)d_in[3];
  const float* bk = (const float*)d_in[4];
  const float* Wv = (const float*)d_in[5];
  const float* bv = (const float*)d_in[6];
  const float* Wp = (const float*)d_in[7];
  const float* bp = (const float*)d_in[8];

  char* ws = (char*)d_ws;
  u16* x16  = (u16*)(ws + (size_t)0);          // 4096x1024 bf16 (reused as y16 later)
  u16* w16  = (u16*)(ws + ((size_t)8  << 20)); // Wq,Wk,Wv,Wp bf16, 1M elems each
  u16* q16  = (u16*)(ws + ((size_t)16 << 20)); // (B,H,T,d)
  u16* k16  = (u16*)(ws + ((size_t)24 << 20)); // (B,H,T,d)
  u16* v16  = (u16*)(ws + ((size_t)32 << 20)); // (B,H,T,d)
  u16* vt16 = (u16*)(ws + ((size_t)40 << 20)); // (B,H,d,T)
  u16* y16  = x16;

  cvt_bf16<<<4096, 256, 0, stream>>>(x,  x16, 1048576);
  cvt_bf16<<<1024, 256, 0, stream>>>(Wq, w16 + 0 * 1048576, 262144);
  cvt_bf16<<<1024, 256, 0, stream>>>(Wk, w16 + 1 * 1048576, 262144);
  cvt_bf16<<<1024, 256, 0, stream>>>(Wv, w16 + 2 * 1048576, 262144);
  cvt_bf16<<<1024, 256, 0, stream>>>(Wp, w16 + 3 * 1048576, 262144);

  gemm_bt<0><<<dim3(8, 32, 3), 256, 0, stream>>>(x16, w16, bq, bk, bv, (void*)q16, 4096, 1024, 1024);
  transpose_v<<<dim3(32, 32), 256, 0, stream>>>(v16, vt16);
  attn_fwd<<<dim3(32, 32), 256, 0, stream>>>(q16, k16, vt16, y16);
  gemm_bt<1><<<dim3(8, 32, 1), 256, 0, stream>>>(y16, w16 + 3 * 1048576, bp, bp, bp, d_out, 4096, 1024, 1024);
}